// Round 3
// baseline (163.834 us; speedup 1.0000x reference)
//
#include <hip/hip_runtime.h>

// LSTM_13451837571407 — MFMA bf16-split, fragment-major LDS (R3).
// R2 postmortem: SQ_LDS_BANK_CONFLICT=4.5e7 from weight ds_read_b64 whose
// per-lane address contained bcol*32B (16-bank aliasing, 4-way conflict).
// Fix: weights stored in MFMA-fragment order: one 16B slot per (l,t,lane)
// holding [Ah(4 bf16) | Al(4 bf16)]. Main loop reads it with a single
// ds_read_b128 at lane*16B stride -> each 16-lane quarter covers all 32
// banks exactly once -> conflict-free.
//
// Math (unchanged from R2, numerically verified absmax=2.4e-4):
//   layer 0: gates = x@W_ih0^T + (b_ih0+b_hh0)        (h=c=0, K padded 14->16)
//   layer l>=1: gates = h@(W_ih[l-1]+W_hh[l])^T + bc  (input==hidden quirk)
//   rows i,f,o scaled by -log2e (sigmoid=1/(1+exp2(y)));
//   rows g scaled by 2log2e (tanh=(exp2(y)-1)/(exp2(y)+1)).
//   W split hi+lo bf16; 3 MFMA products (hh,hl,lh), fp32 accumulate.
// v_mfma_f32_16x16x16_bf16: A row=lane&15,k=4*(lane>>4)+j; B k likewise,
// col=lane&15; D col=lane&15,row=4*(lane>>4)+reg. Lane's D rows == its next
// B-fragment k-slots -> zero cross-lane traffic between layers.

typedef short bf16x4 __attribute__((ext_vector_type(4)));
typedef short bf16x8 __attribute__((ext_vector_type(8)));
typedef float f32x4 __attribute__((ext_vector_type(4)));

#if __has_builtin(__builtin_amdgcn_mfma_f32_16x16x16bf16_1k)
__device__ __forceinline__ f32x4 mfma16(bf16x4 a, bf16x4 b, f32x4 c) {
    return __builtin_amdgcn_mfma_f32_16x16x16bf16_1k(a, b, c, 0, 0, 0);
}
#else
__device__ __forceinline__ f32x4 mfma16(bf16x4 a, bf16x4 b, f32x4 c) {
    asm volatile("v_mfma_f32_16x16x16_bf16 %0, %1, %2, %0\n\ts_nop 7\n\ts_nop 7"
                 : "+v"(c) : "v"(a), "v"(b));
    return c;
}
#endif

#define NLOG2E  (-1.4426950408889634f)
#define G2LOG2E (2.8853900817779268f)
#define THREADS 512
#define WAVES_PB (THREADS / 64)
#define NBLOCKS 1024

__global__ __launch_bounds__(THREADS, 4) void lstm_mfma_kernel(
    const float* __restrict__ x,      // [B][14]
    const float* __restrict__ W_ih0,  // [64][14]
    const float* __restrict__ W_ih,   // [7][64][16]
    const float* __restrict__ W_hh,   // [8][64][16]
    const float* __restrict__ b_ih,   // [8][64]
    const float* __restrict__ b_hh,   // [8][64]
    const float* __restrict__ fc_w,   // [16]
    const float* __restrict__ fc_b,   // [1]
    float* __restrict__ out,          // [B]
    int nB)
{
    // fragment-major: sWF[(l*4+t)*64 + lane] = 8 shorts [Ah0..3, Al0..3]
    __shared__ __align__(16) short sWF[8 * 4 * 64 * 8];  // 32 KB
    __shared__ __align__(16) float sB[8 * 64];           // folded bias (frag order via hi*4)
    __shared__ __align__(16) float sFC[20];

    const int tid = threadIdx.x;

    // ---- weight prep into fragment-major layout ----
    // slot = (l, t, lane): covers gate-rows row=t*16+(lane&15), k=4*(lane>>4)..+3
    for (int slot = tid; slot < 2048; slot += THREADS) {
        const int l = slot >> 8;
        const int t = (slot >> 6) & 3;
        const int ln = slot & 63;
        const int row = t * 16 + (ln & 15);      // row within 64 gate rows
        const int k0 = (ln >> 4) * 4;
        const float scale = (t == 2) ? G2LOG2E : NLOG2E;
        short frag[8];
        #pragma unroll
        for (int j = 0; j < 4; ++j) {
            const int k = k0 + j;
            float w;
            if (l == 0) w = (k < 14) ? W_ih0[row * 14 + k] : 0.0f;
            else        w = W_ih[(l - 1) * 1024 + row * 16 + k]
                          + W_hh[l * 1024 + row * 16 + k];
            w *= scale;
            const unsigned u = __float_as_uint(w);
            frag[j] = (short)(u >> 16);
            const float lo = w - __uint_as_float(u & 0xFFFF0000u);
            frag[4 + j] = (short)(__float_as_uint(lo) >> 16);
        }
        *(short4*)(sWF + slot * 8)     = make_short4(frag[0], frag[1], frag[2], frag[3]);
        *(short4*)(sWF + slot * 8 + 4) = make_short4(frag[4], frag[5], frag[6], frag[7]);
    }
    for (int idx = tid; idx < 512; idx += THREADS) {
        const int row = idx & 63;
        const float scale = ((row >> 4) == 2) ? G2LOG2E : NLOG2E;
        sB[idx] = (b_ih[idx] + b_hh[idx]) * scale;
    }
    if (tid < 16) sFC[tid] = fc_w[tid];
    if (tid == 16) sFC[16] = fc_b[0];
    __syncthreads();

    const int lane = tid & 63;
    const int wv = tid >> 6;
    const int bcol = lane & 15;   // batch within tile
    const int hi = lane >> 4;     // k-quad / D-row group

    const int n_tiles = (nB + 15) >> 4;
    const int waves_total = NBLOCKS * WAVES_PB;
    const int iters = (n_tiles + waves_total - 1) / waves_total;
    const int gw = blockIdx.x * WAVES_PB + wv;

    for (int it = 0; it < iters; ++it) {
        const int tile = gw * iters + it;
        if (tile >= n_tiles) break;
        const int batch = tile * 16 + bcol;
        const int bclamp = batch < nB ? batch : nB - 1;

        // ---- x fragment: lane holds x[b][4hi..4hi+3] (pad 14->16) ----
        float hv[4];
        {
            const float* xr = x + bclamp * 14 + hi * 4;
            const float2 p = *(const float2*)xr;
            hv[0] = p.x; hv[1] = p.y;
            if (hi < 3) {
                const float2 q = *(const float2*)(xr + 2);
                hv[2] = q.x; hv[3] = q.y;
            } else { hv[2] = 0.f; hv[3] = 0.f; }
        }

        bf16x4 Bhh, Bhl;
        #pragma unroll
        for (int r = 0; r < 4; ++r) {
            const unsigned u = __float_as_uint(hv[r]);
            Bhh[r] = (short)(u >> 16);
            const float lo = hv[r] - __uint_as_float(u & 0xFFFF0000u);
            Bhl[r] = (short)(__float_as_uint(lo) >> 16);
        }

        float c[4] = {0.f, 0.f, 0.f, 0.f};

        #pragma unroll
        for (int l = 0; l < 8; ++l) {
            f32x4 acc[4];
            #pragma unroll
            for (int t = 0; t < 4; ++t) {
                // conflict-free: lane*16B stride, (l,t) as immediate offset
                const bf16x8 fr = *(const bf16x8*)(sWF + ((l * 4 + t) << 9) + (lane << 3));
                const bf16x4 Ah = __builtin_shufflevector(fr, fr, 0, 1, 2, 3);
                const bf16x4 Al = __builtin_shufflevector(fr, fr, 4, 5, 6, 7);
                acc[t] = *(const f32x4*)(sB + l * 64 + t * 16 + hi * 4);
                acc[t] = mfma16(Ah, Bhh, acc[t]);
                acc[t] = mfma16(Ah, Bhl, acc[t]);
                acc[t] = mfma16(Al, Bhh, acc[t]);
            }
            // ---- nonlinearity: lane owns units 4hi+r of batch bcol ----
            #pragma unroll
            for (int r = 0; r < 4; ++r) {
                const float yi = acc[0][r];
                const float yf = acc[1][r];
                const float yg = acc[2][r];
                const float yo = acc[3][r];
                const float Di = 1.f + __builtin_amdgcn_exp2f(yi);
                const float Df = 1.f + __builtin_amdgcn_exp2f(yf);
                const float Eg = __builtin_amdgcn_exp2f(yg);
                const float P = Di * (Eg + 1.f);
                const float num = fmaf(Eg - 1.f, Df, c[r] * P);
                const float cr = num * __builtin_amdgcn_rcpf(Df * P);
                c[r] = cr;
                const float Do = 1.f + __builtin_amdgcn_exp2f(yo);
                const float Ec = __builtin_amdgcn_exp2f(cr * G2LOG2E);
                hv[r] = (Ec - 1.f) * __builtin_amdgcn_rcpf(Do * (Ec + 1.f));
            }
            #pragma unroll
            for (int r = 0; r < 4; ++r) {
                const unsigned u = __float_as_uint(hv[r]);
                Bhh[r] = (short)(u >> 16);
                const float lo = hv[r] - __uint_as_float(u & 0xFFFF0000u);
                Bhl[r] = (short)(__float_as_uint(lo) >> 16);
            }
        }

        // ---- FC head, reduce across 4 hi-lanes ----
        const f32x4 fw = *(const f32x4*)(sFC + hi * 4);
        float p = hv[0] * fw[0] + hv[1] * fw[1] + hv[2] * fw[2] + hv[3] * fw[3];
        p += __shfl_xor(p, 16, 64);
        p += __shfl_xor(p, 32, 64);
        if (hi == 0 && batch < nB) out[batch] = p + sFC[16];
    }
}

extern "C" void kernel_launch(void* const* d_in, const int* in_sizes, int n_in,
                              void* d_out, int out_size, void* d_ws, size_t ws_size,
                              hipStream_t stream) {
    const float* x     = (const float*)d_in[0];
    const float* W_ih0 = (const float*)d_in[1];
    const float* W_ih  = (const float*)d_in[2];
    const float* W_hh  = (const float*)d_in[3];
    const float* b_ih  = (const float*)d_in[4];
    const float* b_hh  = (const float*)d_in[5];
    const float* fc_w  = (const float*)d_in[6];
    const float* fc_b  = (const float*)d_in[7];
    float* out = (float*)d_out;

    const int B = in_sizes[0] / 14;
    lstm_mfma_kernel<<<NBLOCKS, THREADS, 0, stream>>>(
        x, W_ih0, W_ih, W_hh, b_ih, b_hh, fc_w, fc_b, out, B);
}

// Round 4
// 144.808 us; speedup vs baseline: 1.1314x; 1.1314x over previous
//
#include <hip/hip_runtime.h>

// LSTM_13451837571407 — R4: 2-tile interleave + fma-tight activation.
// R3 postmortem: bank conflicts were hidden (removing 4.5e7 conflicts changed
// nothing) — kernel is VALU/trans issue+latency bound (VALUBusy 69%, 31% idle).
// R4: each wave processes TWO 16-batch tiles per iteration: weight/bias LDS
// reads shared, two independent activation dependency chains interleave to
// fill trans-pipe latency bubbles. Activation rewritten with fused (E±1) fmas.
//
// Math (verified absmax=2.44e-4 since R2):
//   layer 0: gates = x@W_ih0^T + (b_ih0+b_hh0)        (h=c=0, K padded 14->16)
//   layer l>=1: gates = h@(W_ih[l-1]+W_hh[l])^T + bc  (input==hidden quirk)
//   rows i,f,o scaled by -log2e (sigmoid=1/(1+exp2(y)));
//   rows g scaled by 2log2e (tanh=(exp2(y)-1)/(exp2(y)+1)).
//   W split hi+lo bf16; 3 MFMA products (hh,hl,lh), fp32 accumulate.
// v_mfma_f32_16x16x16_bf16: A row=lane&15,k=4*(lane>>4)+j; B k likewise,
// col=lane&15; D col=lane&15,row=4*(lane>>4)+reg. Lane's D rows == its next
// B-fragment k-slots -> zero cross-lane traffic between layers.

typedef short bf16x4 __attribute__((ext_vector_type(4)));
typedef short bf16x8 __attribute__((ext_vector_type(8)));
typedef float f32x4 __attribute__((ext_vector_type(4)));
typedef unsigned int uint2v __attribute__((ext_vector_type(2)));

#if __has_builtin(__builtin_amdgcn_mfma_f32_16x16x16bf16_1k)
__device__ __forceinline__ f32x4 mfma16(bf16x4 a, bf16x4 b, f32x4 c) {
    return __builtin_amdgcn_mfma_f32_16x16x16bf16_1k(a, b, c, 0, 0, 0);
}
#else
__device__ __forceinline__ f32x4 mfma16(bf16x4 a, bf16x4 b, f32x4 c) {
    asm volatile("v_mfma_f32_16x16x16_bf16 %0, %1, %2, %0\n\ts_nop 7\n\ts_nop 7"
                 : "+v"(c) : "v"(a), "v"(b));
    return c;
}
#endif

#define NLOG2E  (-1.4426950408889634f)
#define G2LOG2E (2.8853900817779268f)
#define THREADS 512
#define WAVES_PB (THREADS / 64)
#define NBLOCKS 1024

// split 4 floats into hi/lo bf16 fragments (packed bit-ops, element j in
// low half of word j/2 — matches weight-prep short4 packing)
__device__ __forceinline__ void split4(const float* h, bf16x4& bh, bf16x4& bl) {
    const unsigned u0 = __float_as_uint(h[0]), u1 = __float_as_uint(h[1]);
    const unsigned u2 = __float_as_uint(h[2]), u3 = __float_as_uint(h[3]);
    uint2v H;
    H[0] = (u0 >> 16) | (u1 & 0xFFFF0000u);
    H[1] = (u2 >> 16) | (u3 & 0xFFFF0000u);
    const float l0 = h[0] - __uint_as_float(u0 & 0xFFFF0000u);
    const float l1 = h[1] - __uint_as_float(u1 & 0xFFFF0000u);
    const float l2 = h[2] - __uint_as_float(u2 & 0xFFFF0000u);
    const float l3 = h[3] - __uint_as_float(u3 & 0xFFFF0000u);
    const unsigned v0 = __float_as_uint(l0), v1 = __float_as_uint(l1);
    const unsigned v2 = __float_as_uint(l2), v3 = __float_as_uint(l3);
    uint2v L;
    L[0] = (v0 >> 16) | (v1 & 0xFFFF0000u);
    L[1] = (v2 >> 16) | (v3 & 0xFFFF0000u);
    bh = __builtin_bit_cast(bf16x4, H);
    bl = __builtin_bit_cast(bf16x4, L);
}

// LSTM nonlinearity for one unit-quad; acc rows: 0=i,1=f,2=g,3=o (pre-scaled)
__device__ __forceinline__ void activate4(const f32x4* a, float* c, float* h) {
    #pragma unroll
    for (int r = 0; r < 4; ++r) {
        const float Ei = __builtin_amdgcn_exp2f(a[0][r]);
        const float Ef = __builtin_amdgcn_exp2f(a[1][r]);
        const float Eg = __builtin_amdgcn_exp2f(a[2][r]);
        const float Eo = __builtin_amdgcn_exp2f(a[3][r]);
        const float Di = 1.f + Ei, Df = 1.f + Ef, Do = 1.f + Eo;
        const float P  = fmaf(Di, Eg, Di);                     // Di*(Eg+1)
        const float num = fmaf(Eg, Df, fmaf(c[r], P, -Df));    // (Eg-1)Df + c*P
        const float R1 = __builtin_amdgcn_rcpf(Df * P);
        const float cr = num * R1;
        c[r] = cr;
        const float Ec = __builtin_amdgcn_exp2f(cr * G2LOG2E);
        const float Q  = fmaf(Do, Ec, Do);                     // Do*(Ec+1)
        const float R2 = __builtin_amdgcn_rcpf(Q);
        h[r] = fmaf(Ec, R2, -R2);                              // (Ec-1)/Q
    }
}

__global__ __launch_bounds__(THREADS, 4) void lstm_mfma_kernel(
    const float* __restrict__ x,      // [B][14]
    const float* __restrict__ W_ih0,  // [64][14]
    const float* __restrict__ W_ih,   // [7][64][16]
    const float* __restrict__ W_hh,   // [8][64][16]
    const float* __restrict__ b_ih,   // [8][64]
    const float* __restrict__ b_hh,   // [8][64]
    const float* __restrict__ fc_w,   // [16]
    const float* __restrict__ fc_b,   // [1]
    float* __restrict__ out,          // [B]
    int nB)
{
    // fragment-major: sWF[(l*4+t)*64 + lane] = 8 shorts [Ah0..3 | Al0..3]
    __shared__ __align__(16) short sWF[8 * 4 * 64 * 8];  // 32 KB
    __shared__ __align__(16) float sB[8 * 64];
    __shared__ __align__(16) float sFC[20];

    const int tid = threadIdx.x;

    for (int slot = tid; slot < 2048; slot += THREADS) {
        const int l = slot >> 8;
        const int t = (slot >> 6) & 3;
        const int ln = slot & 63;
        const int row = t * 16 + (ln & 15);
        const int k0 = (ln >> 4) * 4;
        const float scale = (t == 2) ? G2LOG2E : NLOG2E;
        short frag[8];
        #pragma unroll
        for (int j = 0; j < 4; ++j) {
            const int k = k0 + j;
            float w;
            if (l == 0) w = (k < 14) ? W_ih0[row * 14 + k] : 0.0f;
            else        w = W_ih[(l - 1) * 1024 + row * 16 + k]
                          + W_hh[l * 1024 + row * 16 + k];
            w *= scale;
            const unsigned u = __float_as_uint(w);
            frag[j] = (short)(u >> 16);
            const float lo = w - __uint_as_float(u & 0xFFFF0000u);
            frag[4 + j] = (short)(__float_as_uint(lo) >> 16);
        }
        *(short4*)(sWF + slot * 8)     = make_short4(frag[0], frag[1], frag[2], frag[3]);
        *(short4*)(sWF + slot * 8 + 4) = make_short4(frag[4], frag[5], frag[6], frag[7]);
    }
    for (int idx = tid; idx < 512; idx += THREADS) {
        const int row = idx & 63;
        const float scale = ((row >> 4) == 2) ? G2LOG2E : NLOG2E;
        sB[idx] = (b_ih[idx] + b_hh[idx]) * scale;
    }
    if (tid < 16) sFC[tid] = fc_w[tid];
    if (tid == 16) sFC[16] = fc_b[0];
    __syncthreads();

    const int lane = tid & 63;
    const int wv = tid >> 6;
    const int bcol = lane & 15;   // batch within tile
    const int hi = lane >> 4;     // k-quad / D-row group

    const int n_pairs = (nB + 31) >> 5;
    const int waves_total = NBLOCKS * WAVES_PB;
    const int iters = (n_pairs + waves_total - 1) / waves_total;
    const int gw = blockIdx.x * WAVES_PB + wv;

    const short* wbase = sWF + (lane << 3);
    const float* bbase = sB + hi * 4;

    for (int it = 0; it < iters; ++it) {
        const int pair = gw * iters + it;
        if (pair >= n_pairs) break;
        const int b0 = pair * 32 + bcol;
        const int b1 = b0 + 16;
        const int b0c = b0 < nB ? b0 : nB - 1;
        const int b1c = b1 < nB ? b1 : nB - 1;

        float h0[4], h1[4];
        {
            const float* xr0 = x + b0c * 14 + hi * 4;
            const float* xr1 = x + b1c * 14 + hi * 4;
            const float2 p0 = *(const float2*)xr0;
            const float2 p1 = *(const float2*)xr1;
            h0[0] = p0.x; h0[1] = p0.y;
            h1[0] = p1.x; h1[1] = p1.y;
            if (hi < 3) {
                const float2 q0 = *(const float2*)(xr0 + 2);
                const float2 q1 = *(const float2*)(xr1 + 2);
                h0[2] = q0.x; h0[3] = q0.y;
                h1[2] = q1.x; h1[3] = q1.y;
            } else { h0[2] = h0[3] = h1[2] = h1[3] = 0.f; }
        }

        bf16x4 B0h, B0l, B1h, B1l;
        split4(h0, B0h, B0l);
        split4(h1, B1h, B1l);

        float c0[4] = {0.f, 0.f, 0.f, 0.f};
        float c1[4] = {0.f, 0.f, 0.f, 0.f};

        #pragma unroll
        for (int l = 0; l < 8; ++l) {
            f32x4 a0[4], a1[4];
            #pragma unroll
            for (int t = 0; t < 4; ++t) {
                const bf16x8 fr = *(const bf16x8*)(wbase + ((l * 4 + t) << 9));
                const bf16x4 Ah = __builtin_shufflevector(fr, fr, 0, 1, 2, 3);
                const bf16x4 Al = __builtin_shufflevector(fr, fr, 4, 5, 6, 7);
                const f32x4 bias = *(const f32x4*)(bbase + l * 64 + t * 16);
                f32x4 y0 = bias, y1 = bias;
                y0 = mfma16(Ah, B0h, y0);  y1 = mfma16(Ah, B1h, y1);
                y0 = mfma16(Ah, B0l, y0);  y1 = mfma16(Ah, B1l, y1);
                y0 = mfma16(Al, B0h, y0);  y1 = mfma16(Al, B1h, y1);
                a0[t] = y0; a1[t] = y1;
            }
            activate4(a0, c0, h0);
            activate4(a1, c1, h1);
            split4(h0, B0h, B0l);
            split4(h1, B1h, B1l);
        }

        // ---- FC head: reduce across the 4 hi-lane groups ----
        const f32x4 fw = *(const f32x4*)(sFC + hi * 4);
        float p0 = h0[0] * fw[0] + h0[1] * fw[1] + h0[2] * fw[2] + h0[3] * fw[3];
        float p1 = h1[0] * fw[0] + h1[1] * fw[1] + h1[2] * fw[2] + h1[3] * fw[3];
        p0 += __shfl_xor(p0, 16, 64);
        p0 += __shfl_xor(p0, 32, 64);
        p1 += __shfl_xor(p1, 16, 64);
        p1 += __shfl_xor(p1, 32, 64);
        if (hi == 0) {
            const float fb = sFC[16];
            if (b0 < nB) out[b0] = p0 + fb;
            if (b1 < nB) out[b1] = p1 + fb;
        }
    }
}

extern "C" void kernel_launch(void* const* d_in, const int* in_sizes, int n_in,
                              void* d_out, int out_size, void* d_ws, size_t ws_size,
                              hipStream_t stream) {
    const float* x     = (const float*)d_in[0];
    const float* W_ih0 = (const float*)d_in[1];
    const float* W_ih  = (const float*)d_in[2];
    const float* W_hh  = (const float*)d_in[3];
    const float* b_ih  = (const float*)d_in[4];
    const float* b_hh  = (const float*)d_in[5];
    const float* fc_w  = (const float*)d_in[6];
    const float* fc_b  = (const float*)d_in[7];
    float* out = (float*)d_out;

    const int B = in_sizes[0] / 14;
    lstm_mfma_kernel<<<NBLOCKS, THREADS, 0, stream>>>(
        x, W_ih0, W_ih, W_hh, b_ih, b_hh, fc_w, fc_b, out, B);
}

// Round 5
// 138.574 us; speedup vs baseline: 1.1823x; 1.0450x over previous
//
#include <hip/hip_runtime.h>

// LSTM_13451837571407 — R5: perm-based bf16 split + packed-fp32 activation.
// R4 postmortem: VALU-issue bound (VALUBusy 72%, MfmaUtil 27%, HBM 2%).
// Reducible term = plain-VALU instr count: h-resplit 64 instr/layer -> 20 via
// v_perm_b32; activation fma/mul halved via f32x2 (v_pk_fma_f32) on adjacent
// acc register pairs. Trans count (40 exp2 + 16 rcp per wave-layer) is the
// mathematical floor for exact sigmoid/tanh and unchanged.
//
// Math (verified absmax=2.44e-4 since R2):
//   layer 0: gates = x@W_ih0^T + (b_ih0+b_hh0)        (h=c=0, K padded 14->16)
//   layer l>=1: gates = h@(W_ih[l-1]+W_hh[l])^T + bc  (input==hidden quirk)
//   rows i,f,o scaled by -log2e (sigmoid=1/(1+exp2(y)));
//   rows g scaled by 2log2e (tanh=(exp2(y)-1)/(exp2(y)+1)).
//   W split hi+lo bf16 (truncation); 3 MFMA products (hh,hl,lh), fp32 acc.
// v_mfma_f32_16x16x16_bf16: A row=lane&15,k=4*(lane>>4)+j; B k likewise,
// col=lane&15; D col=lane&15,row=4*(lane>>4)+reg. Lane's D rows == its next
// B-fragment k-slots -> zero cross-lane traffic between layers.

typedef short bf16x4 __attribute__((ext_vector_type(4)));
typedef short bf16x8 __attribute__((ext_vector_type(8)));
typedef float f32x4 __attribute__((ext_vector_type(4)));
typedef float f32x2 __attribute__((ext_vector_type(2)));
typedef unsigned int uint2v __attribute__((ext_vector_type(2)));

#if __has_builtin(__builtin_amdgcn_mfma_f32_16x16x16bf16_1k)
__device__ __forceinline__ f32x4 mfma16(bf16x4 a, bf16x4 b, f32x4 c) {
    return __builtin_amdgcn_mfma_f32_16x16x16bf16_1k(a, b, c, 0, 0, 0);
}
#else
__device__ __forceinline__ f32x4 mfma16(bf16x4 a, bf16x4 b, f32x4 c) {
    asm volatile("v_mfma_f32_16x16x16_bf16 %0, %1, %2, %0\n\ts_nop 7\n\ts_nop 7"
                 : "+v"(c) : "v"(a), "v"(b));
    return c;
}
#endif

#define NLOG2E  (-1.4426950408889634f)
#define G2LOG2E (2.8853900817779268f)
#define THREADS 512
#define WAVES_PB (THREADS / 64)
#define NBLOCKS 1024
#define PSEL 0x07060302u  // v_perm: [b.b2,b.b3,a.b2,a.b3] = pack two bf16-hi

// pack (h01,h23) -> bf16x4 hi fragment + bf16x4 lo fragment (truncation split)
__device__ __forceinline__ void split_pair(f32x2 h01, f32x2 h23,
                                           bf16x4& bh, bf16x4& bl) {
    const unsigned u0 = __float_as_uint(h01[0]), u1 = __float_as_uint(h01[1]);
    const unsigned u2 = __float_as_uint(h23[0]), u3 = __float_as_uint(h23[1]);
    uint2v W;
    W[0] = __builtin_amdgcn_perm(u1, u0, PSEL);
    W[1] = __builtin_amdgcn_perm(u3, u2, PSEL);
    bh = __builtin_bit_cast(bf16x4, W);
    f32x2 g01, g23;
    g01[0] = __uint_as_float(u0 & 0xFFFF0000u);
    g01[1] = __uint_as_float(u1 & 0xFFFF0000u);
    g23[0] = __uint_as_float(u2 & 0xFFFF0000u);
    g23[1] = __uint_as_float(u3 & 0xFFFF0000u);
    const f32x2 l01 = h01 - g01, l23 = h23 - g23;
    const unsigned v0 = __float_as_uint(l01[0]), v1 = __float_as_uint(l01[1]);
    const unsigned v2 = __float_as_uint(l23[0]), v3 = __float_as_uint(l23[1]);
    uint2v L;
    L[0] = __builtin_amdgcn_perm(v1, v0, PSEL);
    L[1] = __builtin_amdgcn_perm(v3, v2, PSEL);
    bl = __builtin_bit_cast(bf16x4, L);
}

// LSTM nonlinearity on a pair of units (packed f32x2 arithmetic).
// inputs pre-scaled: i,f,o by -log2e; g by 2log2e.
__device__ __forceinline__ void act2(f32x2 yi, f32x2 yf, f32x2 yg, f32x2 yo,
                                     f32x2& c, f32x2& h) {
    f32x2 Ei, Ef, Eg, Eo;
    Ei[0] = __builtin_amdgcn_exp2f(yi[0]); Ei[1] = __builtin_amdgcn_exp2f(yi[1]);
    Ef[0] = __builtin_amdgcn_exp2f(yf[0]); Ef[1] = __builtin_amdgcn_exp2f(yf[1]);
    Eg[0] = __builtin_amdgcn_exp2f(yg[0]); Eg[1] = __builtin_amdgcn_exp2f(yg[1]);
    Eo[0] = __builtin_amdgcn_exp2f(yo[0]); Eo[1] = __builtin_amdgcn_exp2f(yo[1]);
    const f32x2 one = {1.f, 1.f};
    const f32x2 Di = Ei + one, Df = Ef + one, Do = Eo + one;
    const f32x2 P = __builtin_elementwise_fma(Di, Eg, Di);           // Di*(Eg+1)
    const f32x2 num = __builtin_elementwise_fma(
        Eg, Df, __builtin_elementwise_fma(c, P, -Df));               // (Eg-1)Df+cP
    const f32x2 DfP = Df * P;
    f32x2 R1;
    R1[0] = __builtin_amdgcn_rcpf(DfP[0]); R1[1] = __builtin_amdgcn_rcpf(DfP[1]);
    c = num * R1;
    const f32x2 cg = c * (f32x2){G2LOG2E, G2LOG2E};
    f32x2 Ec;
    Ec[0] = __builtin_amdgcn_exp2f(cg[0]); Ec[1] = __builtin_amdgcn_exp2f(cg[1]);
    const f32x2 Q = __builtin_elementwise_fma(Do, Ec, Do);           // Do*(Ec+1)
    f32x2 R2;
    R2[0] = __builtin_amdgcn_rcpf(Q[0]); R2[1] = __builtin_amdgcn_rcpf(Q[1]);
    h = __builtin_elementwise_fma(Ec, R2, -R2);                      // (Ec-1)/Q
}

#define LOP(v) __builtin_shufflevector(v, v, 0, 1)
#define HIP2(v) __builtin_shufflevector(v, v, 2, 3)

__global__ __launch_bounds__(THREADS, 4) void lstm_mfma_kernel(
    const float* __restrict__ x,      // [B][14]
    const float* __restrict__ W_ih0,  // [64][14]
    const float* __restrict__ W_ih,   // [7][64][16]
    const float* __restrict__ W_hh,   // [8][64][16]
    const float* __restrict__ b_ih,   // [8][64]
    const float* __restrict__ b_hh,   // [8][64]
    const float* __restrict__ fc_w,   // [16]
    const float* __restrict__ fc_b,   // [1]
    float* __restrict__ out,          // [B]
    int nB)
{
    // fragment-major: sWF[(l*4+t)*64 + lane] = 8 shorts [Ah0..3 | Al0..3]
    __shared__ __align__(16) short sWF[8 * 4 * 64 * 8];  // 32 KB
    __shared__ __align__(16) float sB[8 * 64];
    __shared__ __align__(16) float sFC[20];

    const int tid = threadIdx.x;

    for (int slot = tid; slot < 2048; slot += THREADS) {
        const int l = slot >> 8;
        const int t = (slot >> 6) & 3;
        const int ln = slot & 63;
        const int row = t * 16 + (ln & 15);
        const int k0 = (ln >> 4) * 4;
        const float scale = (t == 2) ? G2LOG2E : NLOG2E;
        short frag[8];
        #pragma unroll
        for (int j = 0; j < 4; ++j) {
            const int k = k0 + j;
            float w;
            if (l == 0) w = (k < 14) ? W_ih0[row * 14 + k] : 0.0f;
            else        w = W_ih[(l - 1) * 1024 + row * 16 + k]
                          + W_hh[l * 1024 + row * 16 + k];
            w *= scale;
            const unsigned u = __float_as_uint(w);
            frag[j] = (short)(u >> 16);
            const float lo = w - __uint_as_float(u & 0xFFFF0000u);
            frag[4 + j] = (short)(__float_as_uint(lo) >> 16);
        }
        *(short4*)(sWF + slot * 8)     = make_short4(frag[0], frag[1], frag[2], frag[3]);
        *(short4*)(sWF + slot * 8 + 4) = make_short4(frag[4], frag[5], frag[6], frag[7]);
    }
    for (int idx = tid; idx < 512; idx += THREADS) {
        const int row = idx & 63;
        const float scale = ((row >> 4) == 2) ? G2LOG2E : NLOG2E;
        sB[idx] = (b_ih[idx] + b_hh[idx]) * scale;
    }
    if (tid < 16) sFC[tid] = fc_w[tid];
    if (tid == 16) sFC[16] = fc_b[0];
    __syncthreads();

    const int lane = tid & 63;
    const int wv = tid >> 6;
    const int bcol = lane & 15;   // batch within tile
    const int hi = lane >> 4;     // k-quad / D-row group

    const int n_pairs = (nB + 31) >> 5;
    const int waves_total = NBLOCKS * WAVES_PB;
    const int iters = (n_pairs + waves_total - 1) / waves_total;
    const int gw = blockIdx.x * WAVES_PB + wv;

    const short* wbase = sWF + (lane << 3);
    const float* bbase = sB + hi * 4;

    // FC weights hoisted (uniform LDS reads, once)
    const f32x4 fw4 = *(const f32x4*)(sFC + hi * 4);
    const f32x2 fwa = LOP(fw4), fwb = HIP2(fw4);
    const float fb = sFC[16];

    for (int it = 0; it < iters; ++it) {
        const int pair = gw * iters + it;
        if (pair >= n_pairs) break;
        const int b0 = pair * 32 + bcol;
        const int b1 = b0 + 16;
        const int b0c = b0 < nB ? b0 : nB - 1;
        const int b1c = b1 < nB ? b1 : nB - 1;

        f32x2 h0a, h0b, h1a, h1b;
        {
            const float* xr0 = x + b0c * 14 + hi * 4;
            const float* xr1 = x + b1c * 14 + hi * 4;
            const float2 p0 = *(const float2*)xr0;
            const float2 p1 = *(const float2*)xr1;
            h0a[0] = p0.x; h0a[1] = p0.y;
            h1a[0] = p1.x; h1a[1] = p1.y;
            if (hi < 3) {
                const float2 q0 = *(const float2*)(xr0 + 2);
                const float2 q1 = *(const float2*)(xr1 + 2);
                h0b[0] = q0.x; h0b[1] = q0.y;
                h1b[0] = q1.x; h1b[1] = q1.y;
            } else { h0b = (f32x2){0.f, 0.f}; h1b = (f32x2){0.f, 0.f}; }
        }

        bf16x4 B0h, B0l, B1h, B1l;
        split_pair(h0a, h0b, B0h, B0l);
        split_pair(h1a, h1b, B1h, B1l);

        f32x2 c0a = {0.f, 0.f}, c0b = {0.f, 0.f};
        f32x2 c1a = {0.f, 0.f}, c1b = {0.f, 0.f};

        #pragma unroll
        for (int l = 0; l < 8; ++l) {
            f32x4 a0[4], a1[4];
            #pragma unroll
            for (int t = 0; t < 4; ++t) {
                const bf16x8 fr = *(const bf16x8*)(wbase + ((l * 4 + t) << 9));
                const bf16x4 Ah = __builtin_shufflevector(fr, fr, 0, 1, 2, 3);
                const bf16x4 Al = __builtin_shufflevector(fr, fr, 4, 5, 6, 7);
                const f32x4 bias = *(const f32x4*)(bbase + l * 64 + t * 16);
                f32x4 y0 = bias, y1 = bias;
                y0 = mfma16(Ah, B0h, y0);  y1 = mfma16(Ah, B1h, y1);
                y0 = mfma16(Ah, B0l, y0);  y1 = mfma16(Ah, B1l, y1);
                y0 = mfma16(Al, B0h, y0);  y1 = mfma16(Al, B1h, y1);
                a0[t] = y0; a1[t] = y1;
            }
            // 4 independent packed activation chains (2 pairs x 2 tiles)
            act2(LOP(a0[0]), LOP(a0[1]), LOP(a0[2]), LOP(a0[3]), c0a, h0a);
            act2(HIP2(a0[0]), HIP2(a0[1]), HIP2(a0[2]), HIP2(a0[3]), c0b, h0b);
            act2(LOP(a1[0]), LOP(a1[1]), LOP(a1[2]), LOP(a1[3]), c1a, h1a);
            act2(HIP2(a1[0]), HIP2(a1[1]), HIP2(a1[2]), HIP2(a1[3]), c1b, h1b);
            split_pair(h0a, h0b, B0h, B0l);
            split_pair(h1a, h1b, B1h, B1l);
        }

        // ---- FC head: dot(h, fc_w), reduce across 4 hi-lane groups ----
        f32x2 s0 = h0a * fwa; s0 = __builtin_elementwise_fma(h0b, fwb, s0);
        f32x2 s1 = h1a * fwa; s1 = __builtin_elementwise_fma(h1b, fwb, s1);
        float p0 = s0[0] + s0[1];
        float p1 = s1[0] + s1[1];
        p0 += __shfl_xor(p0, 16, 64);
        p0 += __shfl_xor(p0, 32, 64);
        p1 += __shfl_xor(p1, 16, 64);
        p1 += __shfl_xor(p1, 32, 64);
        if (hi == 0) {
            if (b0 < nB) out[b0] = p0 + fb;
            if (b1 < nB) out[b1] = p1 + fb;
        }
    }
}

extern "C" void kernel_launch(void* const* d_in, const int* in_sizes, int n_in,
                              void* d_out, int out_size, void* d_ws, size_t ws_size,
                              hipStream_t stream) {
    const float* x     = (const float*)d_in[0];
    const float* W_ih0 = (const float*)d_in[1];
    const float* W_ih  = (const float*)d_in[2];
    const float* W_hh  = (const float*)d_in[3];
    const float* b_ih  = (const float*)d_in[4];
    const float* b_hh  = (const float*)d_in[5];
    const float* fc_w  = (const float*)d_in[6];
    const float* fc_b  = (const float*)d_in[7];
    float* out = (float*)d_out;

    const int B = in_sizes[0] / 14;
    lstm_mfma_kernel<<<NBLOCKS, THREADS, 0, stream>>>(
        x, W_ih0, W_ih, W_hh, b_ih, b_hh, fc_w, fc_b, out, B);
}

// Round 6
// 137.845 us; speedup vs baseline: 1.1885x; 1.0053x over previous
//
#include <hip/hip_runtime.h>

// LSTM_13451837571407 — R6: 4-tile (64 batch/wave) ILP.
// R5 postmortem: VALUBusy fell 72->63% with only -4% time => latency/dependency
// bound, not issue-count bound. Occupancy is LDS-capped (32KB weights -> 4
// blocks/CU, 4 waves/SIMD). Fix: 4 independent 16-batch tiles per wave; weight
// frags + biases loaded once per layer serve all 4 tiles; tile t+1's MFMA
// block overlaps tile t's trans-unit activation chain.
//
// Math (verified absmax=2.44e-4 since R2):
//   layer 0: gates = x@W_ih0^T + (b_ih0+b_hh0)        (h=c=0, K padded 14->16)
//   layer l>=1: gates = h@(W_ih[l-1]+W_hh[l])^T + bc  (input==hidden quirk)
//   rows i,f,o scaled by -log2e (sigmoid=1/(1+exp2(y)));
//   rows g scaled by 2log2e (tanh=(exp2(y)-1)/(exp2(y)+1)).
//   W split hi+lo bf16 (truncation); 3 MFMA products (hh,hl,lh), fp32 acc.
// v_mfma_f32_16x16x16_bf16: A row=lane&15,k=4*(lane>>4)+j; B k likewise,
// col=lane&15; D col=lane&15,row=4*(lane>>4)+reg. Lane's D rows == its next
// B-fragment k-slots -> zero cross-lane traffic between layers.

typedef short bf16x4 __attribute__((ext_vector_type(4)));
typedef short bf16x8 __attribute__((ext_vector_type(8)));
typedef float f32x4 __attribute__((ext_vector_type(4)));
typedef float f32x2 __attribute__((ext_vector_type(2)));
typedef unsigned int uint2v __attribute__((ext_vector_type(2)));

#if __has_builtin(__builtin_amdgcn_mfma_f32_16x16x16bf16_1k)
__device__ __forceinline__ f32x4 mfma16(bf16x4 a, bf16x4 b, f32x4 c) {
    return __builtin_amdgcn_mfma_f32_16x16x16bf16_1k(a, b, c, 0, 0, 0);
}
#else
__device__ __forceinline__ f32x4 mfma16(bf16x4 a, bf16x4 b, f32x4 c) {
    asm volatile("v_mfma_f32_16x16x16_bf16 %0, %1, %2, %0\n\ts_nop 7\n\ts_nop 7"
                 : "+v"(c) : "v"(a), "v"(b));
    return c;
}
#endif

#define NLOG2E  (-1.4426950408889634f)
#define G2LOG2E (2.8853900817779268f)
#define THREADS 512
#define WAVES_PB (THREADS / 64)
#define NBLOCKS 1024
#define NTILES 4
#define PSEL 0x07060302u  // v_perm: pack two bf16-hi from two f32

// pack (h01,h23) -> bf16x4 hi fragment + bf16x4 lo fragment (truncation split)
__device__ __forceinline__ void split_pair(f32x2 h01, f32x2 h23,
                                           bf16x4& bh, bf16x4& bl) {
    const unsigned u0 = __float_as_uint(h01[0]), u1 = __float_as_uint(h01[1]);
    const unsigned u2 = __float_as_uint(h23[0]), u3 = __float_as_uint(h23[1]);
    uint2v W;
    W[0] = __builtin_amdgcn_perm(u1, u0, PSEL);
    W[1] = __builtin_amdgcn_perm(u3, u2, PSEL);
    bh = __builtin_bit_cast(bf16x4, W);
    f32x2 g01, g23;
    g01[0] = __uint_as_float(u0 & 0xFFFF0000u);
    g01[1] = __uint_as_float(u1 & 0xFFFF0000u);
    g23[0] = __uint_as_float(u2 & 0xFFFF0000u);
    g23[1] = __uint_as_float(u3 & 0xFFFF0000u);
    const f32x2 l01 = h01 - g01, l23 = h23 - g23;
    const unsigned v0 = __float_as_uint(l01[0]), v1 = __float_as_uint(l01[1]);
    const unsigned v2 = __float_as_uint(l23[0]), v3 = __float_as_uint(l23[1]);
    uint2v L;
    L[0] = __builtin_amdgcn_perm(v1, v0, PSEL);
    L[1] = __builtin_amdgcn_perm(v3, v2, PSEL);
    bl = __builtin_bit_cast(bf16x4, L);
}

// LSTM nonlinearity on a pair of units (packed f32x2); rows pre-scaled.
__device__ __forceinline__ void act2(f32x2 yi, f32x2 yf, f32x2 yg, f32x2 yo,
                                     f32x2& c, f32x2& h) {
    f32x2 Ei, Ef, Eg, Eo;
    Ei[0] = __builtin_amdgcn_exp2f(yi[0]); Ei[1] = __builtin_amdgcn_exp2f(yi[1]);
    Ef[0] = __builtin_amdgcn_exp2f(yf[0]); Ef[1] = __builtin_amdgcn_exp2f(yf[1]);
    Eg[0] = __builtin_amdgcn_exp2f(yg[0]); Eg[1] = __builtin_amdgcn_exp2f(yg[1]);
    Eo[0] = __builtin_amdgcn_exp2f(yo[0]); Eo[1] = __builtin_amdgcn_exp2f(yo[1]);
    const f32x2 one = {1.f, 1.f};
    const f32x2 Di = Ei + one, Df = Ef + one, Do = Eo + one;
    const f32x2 P = __builtin_elementwise_fma(Di, Eg, Di);           // Di*(Eg+1)
    const f32x2 num = __builtin_elementwise_fma(
        Eg, Df, __builtin_elementwise_fma(c, P, -Df));               // (Eg-1)Df+cP
    const f32x2 DfP = Df * P;
    f32x2 R1;
    R1[0] = __builtin_amdgcn_rcpf(DfP[0]); R1[1] = __builtin_amdgcn_rcpf(DfP[1]);
    c = num * R1;
    const f32x2 cg = c * (f32x2){G2LOG2E, G2LOG2E};
    f32x2 Ec;
    Ec[0] = __builtin_amdgcn_exp2f(cg[0]); Ec[1] = __builtin_amdgcn_exp2f(cg[1]);
    const f32x2 Q = __builtin_elementwise_fma(Do, Ec, Do);           // Do*(Ec+1)
    f32x2 R2;
    R2[0] = __builtin_amdgcn_rcpf(Q[0]); R2[1] = __builtin_amdgcn_rcpf(Q[1]);
    h = __builtin_elementwise_fma(Ec, R2, -R2);                      // (Ec-1)/Q
}

#define LOP(v) __builtin_shufflevector(v, v, 0, 1)
#define HIP2(v) __builtin_shufflevector(v, v, 2, 3)

__global__ __launch_bounds__(THREADS, 4) void lstm_mfma_kernel(
    const float* __restrict__ x,      // [B][14]
    const float* __restrict__ W_ih0,  // [64][14]
    const float* __restrict__ W_ih,   // [7][64][16]
    const float* __restrict__ W_hh,   // [8][64][16]
    const float* __restrict__ b_ih,   // [8][64]
    const float* __restrict__ b_hh,   // [8][64]
    const float* __restrict__ fc_w,   // [16]
    const float* __restrict__ fc_b,   // [1]
    float* __restrict__ out,          // [B]
    int nB)
{
    // fragment-major: sWF[(l*4+t)*64 + lane] = 8 shorts [Ah0..3 | Al0..3]
    __shared__ __align__(16) short sWF[8 * 4 * 64 * 8];  // 32 KB
    __shared__ __align__(16) float sB[8 * 64];
    __shared__ __align__(16) float sFC[20];

    const int tid = threadIdx.x;

    for (int slot = tid; slot < 2048; slot += THREADS) {
        const int l = slot >> 8;
        const int t = (slot >> 6) & 3;
        const int ln = slot & 63;
        const int row = t * 16 + (ln & 15);
        const int k0 = (ln >> 4) * 4;
        const float scale = (t == 2) ? G2LOG2E : NLOG2E;
        short frag[8];
        #pragma unroll
        for (int j = 0; j < 4; ++j) {
            const int k = k0 + j;
            float w;
            if (l == 0) w = (k < 14) ? W_ih0[row * 14 + k] : 0.0f;
            else        w = W_ih[(l - 1) * 1024 + row * 16 + k]
                          + W_hh[l * 1024 + row * 16 + k];
            w *= scale;
            const unsigned u = __float_as_uint(w);
            frag[j] = (short)(u >> 16);
            const float lo = w - __uint_as_float(u & 0xFFFF0000u);
            frag[4 + j] = (short)(__float_as_uint(lo) >> 16);
        }
        *(short4*)(sWF + slot * 8)     = make_short4(frag[0], frag[1], frag[2], frag[3]);
        *(short4*)(sWF + slot * 8 + 4) = make_short4(frag[4], frag[5], frag[6], frag[7]);
    }
    for (int idx = tid; idx < 512; idx += THREADS) {
        const int row = idx & 63;
        const float scale = ((row >> 4) == 2) ? G2LOG2E : NLOG2E;
        sB[idx] = (b_ih[idx] + b_hh[idx]) * scale;
    }
    if (tid < 16) sFC[tid] = fc_w[tid];
    if (tid == 16) sFC[16] = fc_b[0];
    __syncthreads();

    const int lane = tid & 63;
    const int wv = tid >> 6;
    const int bcol = lane & 15;   // batch within tile
    const int hi = lane >> 4;     // k-quad / D-row group

    const int n_grp = (nB + (16 * NTILES - 1)) / (16 * NTILES);
    const int waves_total = NBLOCKS * WAVES_PB;
    const int iters = (n_grp + waves_total - 1) / waves_total;
    const int gw = blockIdx.x * WAVES_PB + wv;

    const short* wbase = sWF + (lane << 3);
    const float* bbase = sB + hi * 4;

    const f32x4 fw4 = *(const f32x4*)(sFC + hi * 4);
    const f32x2 fwa = LOP(fw4), fwb = HIP2(fw4);
    const float fb = sFC[16];

    for (int it = 0; it < iters; ++it) {
        const int grp = gw * iters + it;
        if (grp >= n_grp) break;

        int bidx[NTILES];
        f32x2 ha[NTILES], hb[NTILES];
        bf16x4 Bh[NTILES], Bl[NTILES];
        f32x2 ca[NTILES], cb[NTILES];

        #pragma unroll
        for (int m = 0; m < NTILES; ++m) {
            const int b = grp * (16 * NTILES) + m * 16 + bcol;
            bidx[m] = b;
            const int bc = b < nB ? b : nB - 1;
            const float* xr = x + bc * 14 + hi * 4;
            const float2 p = *(const float2*)xr;
            ha[m][0] = p.x; ha[m][1] = p.y;
            if (hi < 3) {
                const float2 q = *(const float2*)(xr + 2);
                hb[m][0] = q.x; hb[m][1] = q.y;
            } else { hb[m] = (f32x2){0.f, 0.f}; }
            split_pair(ha[m], hb[m], Bh[m], Bl[m]);
            ca[m] = (f32x2){0.f, 0.f};
            cb[m] = (f32x2){0.f, 0.f};
        }

        #pragma unroll
        for (int l = 0; l < 8; ++l) {
            // shared per-layer loads: 4 weight frags + 4 bias quads
            bf16x4 Ah[4], Al[4];
            f32x4 bias[4];
            #pragma unroll
            for (int t = 0; t < 4; ++t) {
                const bf16x8 fr = *(const bf16x8*)(wbase + ((l * 4 + t) << 9));
                Ah[t] = __builtin_shufflevector(fr, fr, 0, 1, 2, 3);
                Al[t] = __builtin_shufflevector(fr, fr, 4, 5, 6, 7);
                bias[t] = *(const f32x4*)(bbase + l * 64 + t * 16);
            }
            // per-tile MFMA block + activation; tile m+1's MFMAs overlap
            // tile m's trans-chain
            #pragma unroll
            for (int m = 0; m < NTILES; ++m) {
                f32x4 a[4];
                #pragma unroll
                for (int t = 0; t < 4; ++t) {
                    f32x4 y = bias[t];
                    y = mfma16(Ah[t], Bh[m], y);
                    y = mfma16(Ah[t], Bl[m], y);
                    y = mfma16(Al[t], Bh[m], y);
                    a[t] = y;
                }
                act2(LOP(a[0]), LOP(a[1]), LOP(a[2]), LOP(a[3]), ca[m], ha[m]);
                act2(HIP2(a[0]), HIP2(a[1]), HIP2(a[2]), HIP2(a[3]), cb[m], hb[m]);
                split_pair(ha[m], hb[m], Bh[m], Bl[m]);
            }
        }

        // ---- FC head: dot(h, fc_w), reduce across 4 hi-lane groups ----
        #pragma unroll
        for (int m = 0; m < NTILES; ++m) {
            f32x2 s = ha[m] * fwa;
            s = __builtin_elementwise_fma(hb[m], fwb, s);
            float p = s[0] + s[1];
            p += __shfl_xor(p, 16, 64);
            p += __shfl_xor(p, 32, 64);
            if (hi == 0 && bidx[m] < nB) out[bidx[m]] = p + fb;
        }
    }
}

extern "C" void kernel_launch(void* const* d_in, const int* in_sizes, int n_in,
                              void* d_out, int out_size, void* d_ws, size_t ws_size,
                              hipStream_t stream) {
    const float* x     = (const float*)d_in[0];
    const float* W_ih0 = (const float*)d_in[1];
    const float* W_ih  = (const float*)d_in[2];
    const float* W_hh  = (const float*)d_in[3];
    const float* b_ih  = (const float*)d_in[4];
    const float* b_hh  = (const float*)d_in[5];
    const float* fc_w  = (const float*)d_in[6];
    const float* fc_b  = (const float*)d_in[7];
    float* out = (float*)d_out;

    const int B = in_sizes[0] / 14;
    lstm_mfma_kernel<<<NBLOCKS, THREADS, 0, stream>>>(
        x, W_ih0, W_ih, W_hh, b_ih, b_hh, fc_w, fc_b, out, B);
}

// Round 7
// 123.417 us; speedup vs baseline: 1.3275x; 1.1169x over previous
//
#include <hip/hip_runtime.h>

// LSTM_13451837571407 — R7: K32-MFMA fusion (12 -> 8 MFMA per tile-layer).
// R6 postmortem: ILP(4-tile)⇄occupancy trade is a wash; issue model says
// per tile-layer ≈ 28 trans×8cy + 12 MFMA×8cy + ~50 VALU×2cy; trans is at
// math floor -> cut MFMA issue. v_mfma_f32_16x16x32_bf16 with A=[Wh|Wl]
// (our stored 8-short fragment, unchanged LDS) and B=[hh|hh] (lane's own
// quad duplicated) computes Wh·hh + Wl·hh in ONE instruction, assuming the
// gfx950 K32 fragment = two stacked K16 fragments (k = 4*hi + (j&3) +
// 16*(j>>2)). Cross term Wh·hl stays one K16. Identical products => absmax
// must stay exactly 2.441e-4 — this is the layout probe.
//
// Math (verified since R2):
//   layer 0: gates = x@W_ih0^T + (b_ih0+b_hh0)        (h=c=0, K padded 14->16)
//   layer l>=1: gates = h@(W_ih[l-1]+W_hh[l])^T + bc  (input==hidden quirk)
//   rows i,f,o scaled by -log2e (sigmoid=1/(1+exp2(y)));
//   rows g scaled by 2log2e (tanh=(exp2(y)-1)/(exp2(y)+1)).
//   W split hi+lo bf16 (truncation); products Wh·hh + Wl·hh + Wh·hl, fp32 acc.
// v_mfma_f32_16x16x16_bf16: A row=lane&15,k=4*(lane>>4)+j; B k likewise,
// col=lane&15; D col=lane&15,row=4*(lane>>4)+reg. Lane's D rows == its next
// B-fragment k-slots -> zero cross-lane traffic between layers.

typedef short bf16x4 __attribute__((ext_vector_type(4)));
typedef short bf16x8 __attribute__((ext_vector_type(8)));
typedef float f32x4 __attribute__((ext_vector_type(4)));
typedef float f32x2 __attribute__((ext_vector_type(2)));
typedef unsigned int uint2v __attribute__((ext_vector_type(2)));

#if __has_builtin(__builtin_amdgcn_mfma_f32_16x16x16bf16_1k)
__device__ __forceinline__ f32x4 mfma16(bf16x4 a, bf16x4 b, f32x4 c) {
    return __builtin_amdgcn_mfma_f32_16x16x16bf16_1k(a, b, c, 0, 0, 0);
}
#else
__device__ __forceinline__ f32x4 mfma16(bf16x4 a, bf16x4 b, f32x4 c) {
    asm volatile("v_mfma_f32_16x16x16_bf16 %0, %1, %2, %0\n\ts_nop 7\n\ts_nop 7"
                 : "+v"(c) : "v"(a), "v"(b));
    return c;
}
#endif

#if __has_builtin(__builtin_amdgcn_mfma_f32_16x16x32_bf16)
#define HAVE_K32 1
__device__ __forceinline__ f32x4 mfma32(bf16x8 a, bf16x8 b, f32x4 c) {
    return __builtin_amdgcn_mfma_f32_16x16x32_bf16(a, b, c, 0, 0, 0);
}
#endif

#define NLOG2E  (-1.4426950408889634f)
#define G2LOG2E (2.8853900817779268f)
#define THREADS 512
#define WAVES_PB (THREADS / 64)
#define NBLOCKS 1024
#define NTILES 2
#define PSEL 0x07060302u  // v_perm: pack two bf16-hi from two f32

// pack (h01,h23) -> bf16x4 hi fragment + bf16x4 lo fragment (truncation split)
__device__ __forceinline__ void split_pair(f32x2 h01, f32x2 h23,
                                           bf16x4& bh, bf16x4& bl) {
    const unsigned u0 = __float_as_uint(h01[0]), u1 = __float_as_uint(h01[1]);
    const unsigned u2 = __float_as_uint(h23[0]), u3 = __float_as_uint(h23[1]);
    uint2v W;
    W[0] = __builtin_amdgcn_perm(u1, u0, PSEL);
    W[1] = __builtin_amdgcn_perm(u3, u2, PSEL);
    bh = __builtin_bit_cast(bf16x4, W);
    f32x2 g01, g23;
    g01[0] = __uint_as_float(u0 & 0xFFFF0000u);
    g01[1] = __uint_as_float(u1 & 0xFFFF0000u);
    g23[0] = __uint_as_float(u2 & 0xFFFF0000u);
    g23[1] = __uint_as_float(u3 & 0xFFFF0000u);
    const f32x2 l01 = h01 - g01, l23 = h23 - g23;
    const unsigned v0 = __float_as_uint(l01[0]), v1 = __float_as_uint(l01[1]);
    const unsigned v2 = __float_as_uint(l23[0]), v3 = __float_as_uint(l23[1]);
    uint2v L;
    L[0] = __builtin_amdgcn_perm(v1, v0, PSEL);
    L[1] = __builtin_amdgcn_perm(v3, v2, PSEL);
    bl = __builtin_bit_cast(bf16x4, L);
}

// LSTM nonlinearity on a pair of units (packed f32x2); rows pre-scaled.
__device__ __forceinline__ void act2(f32x2 yi, f32x2 yf, f32x2 yg, f32x2 yo,
                                     f32x2& c, f32x2& h) {
    f32x2 Ei, Ef, Eg, Eo;
    Ei[0] = __builtin_amdgcn_exp2f(yi[0]); Ei[1] = __builtin_amdgcn_exp2f(yi[1]);
    Ef[0] = __builtin_amdgcn_exp2f(yf[0]); Ef[1] = __builtin_amdgcn_exp2f(yf[1]);
    Eg[0] = __builtin_amdgcn_exp2f(yg[0]); Eg[1] = __builtin_amdgcn_exp2f(yg[1]);
    Eo[0] = __builtin_amdgcn_exp2f(yo[0]); Eo[1] = __builtin_amdgcn_exp2f(yo[1]);
    const f32x2 one = {1.f, 1.f};
    const f32x2 Di = Ei + one, Df = Ef + one, Do = Eo + one;
    const f32x2 P = __builtin_elementwise_fma(Di, Eg, Di);           // Di*(Eg+1)
    const f32x2 num = __builtin_elementwise_fma(
        Eg, Df, __builtin_elementwise_fma(c, P, -Df));               // (Eg-1)Df+cP
    const f32x2 DfP = Df * P;
    f32x2 R1;
    R1[0] = __builtin_amdgcn_rcpf(DfP[0]); R1[1] = __builtin_amdgcn_rcpf(DfP[1]);
    c = num * R1;
    const f32x2 cg = c * (f32x2){G2LOG2E, G2LOG2E};
    f32x2 Ec;
    Ec[0] = __builtin_amdgcn_exp2f(cg[0]); Ec[1] = __builtin_amdgcn_exp2f(cg[1]);
    const f32x2 Q = __builtin_elementwise_fma(Do, Ec, Do);           // Do*(Ec+1)
    f32x2 R2;
    R2[0] = __builtin_amdgcn_rcpf(Q[0]); R2[1] = __builtin_amdgcn_rcpf(Q[1]);
    h = __builtin_elementwise_fma(Ec, R2, -R2);                      // (Ec-1)/Q
}

#define LOP(v) __builtin_shufflevector(v, v, 0, 1)
#define HIP2(v) __builtin_shufflevector(v, v, 2, 3)

__global__ __launch_bounds__(THREADS, 4) void lstm_mfma_kernel(
    const float* __restrict__ x,      // [B][14]
    const float* __restrict__ W_ih0,  // [64][14]
    const float* __restrict__ W_ih,   // [7][64][16]
    const float* __restrict__ W_hh,   // [8][64][16]
    const float* __restrict__ b_ih,   // [8][64]
    const float* __restrict__ b_hh,   // [8][64]
    const float* __restrict__ fc_w,   // [16]
    const float* __restrict__ fc_b,   // [1]
    float* __restrict__ out,          // [B]
    int nB)
{
    // fragment-major: sWF[(l*4+t)*64 + lane] = 8 shorts [Ah0..3 | Al0..3]
    __shared__ __align__(16) short sWF[8 * 4 * 64 * 8];  // 32 KB
    __shared__ __align__(16) float sB[8 * 64];
    __shared__ __align__(16) float sFC[20];

    const int tid = threadIdx.x;

    for (int slot = tid; slot < 2048; slot += THREADS) {
        const int l = slot >> 8;
        const int t = (slot >> 6) & 3;
        const int ln = slot & 63;
        const int row = t * 16 + (ln & 15);
        const int k0 = (ln >> 4) * 4;
        const float scale = (t == 2) ? G2LOG2E : NLOG2E;
        short frag[8];
        #pragma unroll
        for (int j = 0; j < 4; ++j) {
            const int k = k0 + j;
            float w;
            if (l == 0) w = (k < 14) ? W_ih0[row * 14 + k] : 0.0f;
            else        w = W_ih[(l - 1) * 1024 + row * 16 + k]
                          + W_hh[l * 1024 + row * 16 + k];
            w *= scale;
            const unsigned u = __float_as_uint(w);
            frag[j] = (short)(u >> 16);
            const float lo = w - __uint_as_float(u & 0xFFFF0000u);
            frag[4 + j] = (short)(__float_as_uint(lo) >> 16);
        }
        *(short4*)(sWF + slot * 8)     = make_short4(frag[0], frag[1], frag[2], frag[3]);
        *(short4*)(sWF + slot * 8 + 4) = make_short4(frag[4], frag[5], frag[6], frag[7]);
    }
    for (int idx = tid; idx < 512; idx += THREADS) {
        const int row = idx & 63;
        const float scale = ((row >> 4) == 2) ? G2LOG2E : NLOG2E;
        sB[idx] = (b_ih[idx] + b_hh[idx]) * scale;
    }
    if (tid < 16) sFC[tid] = fc_w[tid];
    if (tid == 16) sFC[16] = fc_b[0];
    __syncthreads();

    const int lane = tid & 63;
    const int wv = tid >> 6;
    const int bcol = lane & 15;   // batch within tile
    const int hi = lane >> 4;     // k-quad / D-row group

    const int n_grp = (nB + (16 * NTILES - 1)) / (16 * NTILES);
    const int waves_total = NBLOCKS * WAVES_PB;
    const int iters = (n_grp + waves_total - 1) / waves_total;
    const int gw = blockIdx.x * WAVES_PB + wv;

    const short* wbase = sWF + (lane << 3);
    const float* bbase = sB + hi * 4;

    const f32x4 fw4 = *(const f32x4*)(sFC + hi * 4);
    const f32x2 fwa = LOP(fw4), fwb = HIP2(fw4);
    const float fb = sFC[16];

    for (int it = 0; it < iters; ++it) {
        const int grp = gw * iters + it;
        if (grp >= n_grp) break;

        int bidx[NTILES];
        f32x2 ha[NTILES], hb[NTILES];
        bf16x4 Bh[NTILES], Bl[NTILES];
        f32x2 ca[NTILES], cb[NTILES];

        #pragma unroll
        for (int m = 0; m < NTILES; ++m) {
            const int b = grp * (16 * NTILES) + m * 16 + bcol;
            bidx[m] = b;
            const int bc = b < nB ? b : nB - 1;
            const float* xr = x + bc * 14 + hi * 4;
            const float2 p = *(const float2*)xr;
            ha[m][0] = p.x; ha[m][1] = p.y;
            if (hi < 3) {
                const float2 q = *(const float2*)(xr + 2);
                hb[m][0] = q.x; hb[m][1] = q.y;
            } else { hb[m] = (f32x2){0.f, 0.f}; }
            split_pair(ha[m], hb[m], Bh[m], Bl[m]);
            ca[m] = (f32x2){0.f, 0.f};
            cb[m] = (f32x2){0.f, 0.f};
        }

        #pragma unroll
        for (int l = 0; l < 8; ++l) {
            // shared per-layer loads: 4 weight frags [Ah|Al] + 4 bias quads
            bf16x8 fr[4];
            f32x4 bias[4];
            #pragma unroll
            for (int t = 0; t < 4; ++t) {
                fr[t] = *(const bf16x8*)(wbase + ((l * 4 + t) << 9));
                bias[t] = *(const f32x4*)(bbase + l * 64 + t * 16);
            }
            #pragma unroll
            for (int m = 0; m < NTILES; ++m) {
#ifdef HAVE_K32
                const bf16x8 Bdup = __builtin_shufflevector(
                    Bh[m], Bh[m], 0, 1, 2, 3, 0, 1, 2, 3);
#endif
                f32x4 a[4];
                #pragma unroll
                for (int t = 0; t < 4; ++t) {
                    f32x4 y = bias[t];
                    const bf16x4 Ah = __builtin_shufflevector(fr[t], fr[t], 0, 1, 2, 3);
#ifdef HAVE_K32
                    y = mfma32(fr[t], Bdup, y);       // Wh·hh + Wl·hh
                    y = mfma16(Ah, Bl[m], y);         // Wh·hl
#else
                    const bf16x4 Al = __builtin_shufflevector(fr[t], fr[t], 4, 5, 6, 7);
                    y = mfma16(Ah, Bh[m], y);
                    y = mfma16(Ah, Bl[m], y);
                    y = mfma16(Al, Bh[m], y);
#endif
                    a[t] = y;
                }
                act2(LOP(a[0]), LOP(a[1]), LOP(a[2]), LOP(a[3]), ca[m], ha[m]);
                act2(HIP2(a[0]), HIP2(a[1]), HIP2(a[2]), HIP2(a[3]), cb[m], hb[m]);
                split_pair(ha[m], hb[m], Bh[m], Bl[m]);
            }
        }

        // ---- FC head: dot(h, fc_w), reduce across 4 hi-lane groups ----
        #pragma unroll
        for (int m = 0; m < NTILES; ++m) {
            f32x2 s = ha[m] * fwa;
            s = __builtin_elementwise_fma(hb[m], fwb, s);
            float p = s[0] + s[1];
            p += __shfl_xor(p, 16, 64);
            p += __shfl_xor(p, 32, 64);
            if (hi == 0 && bidx[m] < nB) out[bidx[m]] = p + fb;
        }
    }
}

extern "C" void kernel_launch(void* const* d_in, const int* in_sizes, int n_in,
                              void* d_out, int out_size, void* d_ws, size_t ws_size,
                              hipStream_t stream) {
    const float* x     = (const float*)d_in[0];
    const float* W_ih0 = (const float*)d_in[1];
    const float* W_ih  = (const float*)d_in[2];
    const float* W_hh  = (const float*)d_in[3];
    const float* b_ih  = (const float*)d_in[4];
    const float* b_hh  = (const float*)d_in[5];
    const float* fc_w  = (const float*)d_in[6];
    const float* fc_b  = (const float*)d_in[7];
    float* out = (float*)d_out;

    const int B = in_sizes[0] / 14;
    lstm_mfma_kernel<<<NBLOCKS, THREADS, 0, stream>>>(
        x, W_ih0, W_ih, W_hh, b_ih, b_hh, fc_w, fc_b, out, B);
}

// Round 8
// 114.170 us; speedup vs baseline: 1.4350x; 1.0810x over previous
//
#include <hip/hip_runtime.h>

// LSTM_13451837571407 — R8: fp16 MFMA (4 MFMA/tile-layer, cvt-only h repack).
// R7 proved the K32 fragment = two stacked K16 fragments (absmax bit-stable).
// R8 theory: measured absmax 2.441e-4 is the output quantization floor, not
// compute error -> spend accuracy: W = fp16_hi + fp16_lo (22 bits), h = single
// fp16 (12 bits). One v_mfma_f32_16x16x32_f16 with A=[Wh|Wl], B=[hf|hf]
// computes (Wh+Wl)·hf per gate-quadrant: MFMA 8->4 per tile-layer, and the
// 10-op bf16 hi/lo repack of h becomes 4 v_cvt_f16_f32.
//
// Math:
//   layer 0: gates = x@W_ih0^T + (b_ih0+b_hh0)        (h=c=0, K padded 14->16)
//   layer l>=1: gates = h@(W_ih[l-1]+W_hh[l])^T + bc  (input==hidden quirk)
//   rows i,f,o scaled by -log2e (sigmoid=1/(1+exp2(y)));
//   rows g scaled by 2log2e (tanh=(exp2(y)-1)/(exp2(y)+1)).
// v_mfma_f32_16x16x{16,32}: A row=lane&15, k=4*(lane>>4)+j (K32: +16*(j>>2));
// B transposed same; D col=lane&15, row=4*(lane>>4)+reg. Lane's D rows == its
// next-layer B k-slots -> zero cross-lane traffic between layers.

typedef _Float16 f16x8 __attribute__((ext_vector_type(8)));
typedef float f32x4 __attribute__((ext_vector_type(4)));
typedef float f32x2 __attribute__((ext_vector_type(2)));

#if __has_builtin(__builtin_amdgcn_mfma_f32_16x16x32_f16)
__device__ __forceinline__ f32x4 mfma32h(f16x8 a, f16x8 b, f32x4 c) {
    return __builtin_amdgcn_mfma_f32_16x16x32_f16(a, b, c, 0, 0, 0);
}
#else
__device__ __forceinline__ f32x4 mfma32h(f16x8 a, f16x8 b, f32x4 c) {
    asm volatile("v_mfma_f32_16x16x32_f16 %0, %1, %2, %0\n\ts_nop 7\n\ts_nop 7"
                 : "+v"(c) : "v"(a), "v"(b));
    return c;
}
#endif

#define NLOG2E  (-1.4426950408889634f)
#define G2LOG2E (2.8853900817779268f)
#define THREADS 512
#define WAVES_PB (THREADS / 64)
#define NBLOCKS 1024
#define NTILES 2

// LSTM nonlinearity on a pair of units (packed f32x2); rows pre-scaled.
__device__ __forceinline__ void act2(f32x2 yi, f32x2 yf, f32x2 yg, f32x2 yo,
                                     f32x2& c, f32x2& h) {
    f32x2 Ei, Ef, Eg, Eo;
    Ei[0] = __builtin_amdgcn_exp2f(yi[0]); Ei[1] = __builtin_amdgcn_exp2f(yi[1]);
    Ef[0] = __builtin_amdgcn_exp2f(yf[0]); Ef[1] = __builtin_amdgcn_exp2f(yf[1]);
    Eg[0] = __builtin_amdgcn_exp2f(yg[0]); Eg[1] = __builtin_amdgcn_exp2f(yg[1]);
    Eo[0] = __builtin_amdgcn_exp2f(yo[0]); Eo[1] = __builtin_amdgcn_exp2f(yo[1]);
    const f32x2 one = {1.f, 1.f};
    const f32x2 Di = Ei + one, Df = Ef + one, Do = Eo + one;
    const f32x2 P = __builtin_elementwise_fma(Di, Eg, Di);           // Di*(Eg+1)
    const f32x2 num = __builtin_elementwise_fma(
        Eg, Df, __builtin_elementwise_fma(c, P, -Df));               // (Eg-1)Df+cP
    const f32x2 DfP = Df * P;
    f32x2 R1;
    R1[0] = __builtin_amdgcn_rcpf(DfP[0]); R1[1] = __builtin_amdgcn_rcpf(DfP[1]);
    c = num * R1;
    const f32x2 cg = c * (f32x2){G2LOG2E, G2LOG2E};
    f32x2 Ec;
    Ec[0] = __builtin_amdgcn_exp2f(cg[0]); Ec[1] = __builtin_amdgcn_exp2f(cg[1]);
    const f32x2 Q = __builtin_elementwise_fma(Do, Ec, Do);           // Do*(Ec+1)
    f32x2 R2;
    R2[0] = __builtin_amdgcn_rcpf(Q[0]); R2[1] = __builtin_amdgcn_rcpf(Q[1]);
    h = __builtin_elementwise_fma(Ec, R2, -R2);                      // (Ec-1)/Q
}

#define LOP(v) __builtin_shufflevector(v, v, 0, 1)
#define HIP2(v) __builtin_shufflevector(v, v, 2, 3)

// duplicate-quad fp16 B fragment: [h0..h3 | h0..h3]
__device__ __forceinline__ f16x8 make_bfrag(f32x2 ha, f32x2 hb) {
    const _Float16 q0 = (_Float16)ha[0], q1 = (_Float16)ha[1];
    const _Float16 q2 = (_Float16)hb[0], q3 = (_Float16)hb[1];
    return (f16x8){q0, q1, q2, q3, q0, q1, q2, q3};
}

__global__ __launch_bounds__(THREADS, 4) void lstm_mfma_kernel(
    const float* __restrict__ x,      // [B][14]
    const float* __restrict__ W_ih0,  // [64][14]
    const float* __restrict__ W_ih,   // [7][64][16]
    const float* __restrict__ W_hh,   // [8][64][16]
    const float* __restrict__ b_ih,   // [8][64]
    const float* __restrict__ b_hh,   // [8][64]
    const float* __restrict__ fc_w,   // [16]
    const float* __restrict__ fc_b,   // [1]
    float* __restrict__ out,          // [B]
    int nB)
{
    // fragment-major: sWF[(l*4+t)*64 + lane] = 8 halfs [Wh0..3 | Wl0..3]
    __shared__ __align__(16) short sWF[8 * 4 * 64 * 8];  // 32 KB
    __shared__ __align__(16) float sB[8 * 64];
    __shared__ __align__(16) float sFC[20];

    const int tid = threadIdx.x;

    for (int slot = tid; slot < 2048; slot += THREADS) {
        const int l = slot >> 8;
        const int t = (slot >> 6) & 3;
        const int ln = slot & 63;
        const int row = t * 16 + (ln & 15);
        const int k0 = (ln >> 4) * 4;
        const float scale = (t == 2) ? G2LOG2E : NLOG2E;
        short frag[8];
        #pragma unroll
        for (int j = 0; j < 4; ++j) {
            const int k = k0 + j;
            float w;
            if (l == 0) w = (k < 14) ? W_ih0[row * 14 + k] : 0.0f;
            else        w = W_ih[(l - 1) * 1024 + row * 16 + k]
                          + W_hh[l * 1024 + row * 16 + k];
            w *= scale;
            const _Float16 wh = (_Float16)w;            // RNE fp16 hi
            const float wres = w - (float)wh;
            const _Float16 wl = (_Float16)wres;         // fp16 lo (22 bits total)
            frag[j]     = __builtin_bit_cast(short, wh);
            frag[4 + j] = __builtin_bit_cast(short, wl);
        }
        *(short4*)(sWF + slot * 8)     = make_short4(frag[0], frag[1], frag[2], frag[3]);
        *(short4*)(sWF + slot * 8 + 4) = make_short4(frag[4], frag[5], frag[6], frag[7]);
    }
    for (int idx = tid; idx < 512; idx += THREADS) {
        const int row = idx & 63;
        const float scale = ((row >> 4) == 2) ? G2LOG2E : NLOG2E;
        sB[idx] = (b_ih[idx] + b_hh[idx]) * scale;
    }
    if (tid < 16) sFC[tid] = fc_w[tid];
    if (tid == 16) sFC[16] = fc_b[0];
    __syncthreads();

    const int lane = tid & 63;
    const int wv = tid >> 6;
    const int bcol = lane & 15;   // batch within tile
    const int hi = lane >> 4;     // k-quad / D-row group

    const int n_grp = (nB + (16 * NTILES - 1)) / (16 * NTILES);
    const int waves_total = NBLOCKS * WAVES_PB;
    const int iters = (n_grp + waves_total - 1) / waves_total;
    const int gw = blockIdx.x * WAVES_PB + wv;

    const short* wbase = sWF + (lane << 3);
    const float* bbase = sB + hi * 4;

    const f32x4 fw4 = *(const f32x4*)(sFC + hi * 4);
    const f32x2 fwa = LOP(fw4), fwb = HIP2(fw4);
    const float fb = sFC[16];

    for (int it = 0; it < iters; ++it) {
        const int grp = gw * iters + it;
        if (grp >= n_grp) break;

        int bidx[NTILES];
        f32x2 ha[NTILES], hb[NTILES];
        f16x8 Bf[NTILES];
        f32x2 ca[NTILES], cb[NTILES];

        #pragma unroll
        for (int m = 0; m < NTILES; ++m) {
            const int b = grp * (16 * NTILES) + m * 16 + bcol;
            bidx[m] = b;
            const int bc = b < nB ? b : nB - 1;
            const float* xr = x + bc * 14 + hi * 4;
            const float2 p = *(const float2*)xr;
            ha[m][0] = p.x; ha[m][1] = p.y;
            if (hi < 3) {
                const float2 q = *(const float2*)(xr + 2);
                hb[m][0] = q.x; hb[m][1] = q.y;
            } else { hb[m] = (f32x2){0.f, 0.f}; }
            Bf[m] = make_bfrag(ha[m], hb[m]);
            ca[m] = (f32x2){0.f, 0.f};
            cb[m] = (f32x2){0.f, 0.f};
        }

        #pragma unroll
        for (int l = 0; l < 8; ++l) {
            // shared per-layer loads: 4 weight frags [Wh|Wl] + 4 bias quads
            f16x8 fr[4];
            f32x4 bias[4];
            #pragma unroll
            for (int t = 0; t < 4; ++t) {
                fr[t] = *(const f16x8*)(wbase + ((l * 4 + t) << 9));
                bias[t] = *(const f32x4*)(bbase + l * 64 + t * 16);
            }
            #pragma unroll
            for (int m = 0; m < NTILES; ++m) {
                f32x4 a[4];
                #pragma unroll
                for (int t = 0; t < 4; ++t) {
                    // (Wh+Wl)·hf in one K32 MFMA (two stacked K16 fragments)
                    a[t] = mfma32h(fr[t], Bf[m], bias[t]);
                }
                act2(LOP(a[0]), LOP(a[1]), LOP(a[2]), LOP(a[3]), ca[m], ha[m]);
                act2(HIP2(a[0]), HIP2(a[1]), HIP2(a[2]), HIP2(a[3]), cb[m], hb[m]);
                Bf[m] = make_bfrag(ha[m], hb[m]);
            }
        }

        // ---- FC head: dot(h, fc_w), reduce across 4 hi-lane groups ----
        #pragma unroll
        for (int m = 0; m < NTILES; ++m) {
            f32x2 s = ha[m] * fwa;
            s = __builtin_elementwise_fma(hb[m], fwb, s);
            float p = s[0] + s[1];
            p += __shfl_xor(p, 16, 64);
            p += __shfl_xor(p, 32, 64);
            if (hi == 0 && bidx[m] < nB) out[bidx[m]] = p + fb;
        }
    }
}

extern "C" void kernel_launch(void* const* d_in, const int* in_sizes, int n_in,
                              void* d_out, int out_size, void* d_ws, size_t ws_size,
                              hipStream_t stream) {
    const float* x     = (const float*)d_in[0];
    const float* W_ih0 = (const float*)d_in[1];
    const float* W_ih  = (const float*)d_in[2];
    const float* W_hh  = (const float*)d_in[3];
    const float* b_ih  = (const float*)d_in[4];
    const float* b_hh  = (const float*)d_in[5];
    const float* fc_w  = (const float*)d_in[6];
    const float* fc_b  = (const float*)d_in[7];
    float* out = (float*)d_out;

    const int B = in_sizes[0] / 14;
    lstm_mfma_kernel<<<NBLOCKS, THREADS, 0, stream>>>(
        x, W_ih0, W_ih, W_hh, b_ih, b_hh, fc_w, fc_b, out, B);
}

// Round 9
// 103.859 us; speedup vs baseline: 1.5775x; 1.0993x over previous
//
#include <hip/hip_runtime.h>

// LSTM_13451837571407 — R9: 1024-thread blocks for full wave occupancy.
// R8 postmortem: issue ≈72µs, busy ≈84µs, wall 130µs -> 35% dependency stall;
// trans (28/tile-layer) is at math floor; OccupancyPercent stuck ~50% (16
// waves/CU). THREADS=1024 keeps LDS/block at 34.5KB (weights shared wider):
// 2 blocks/CU = 32 waves/CU = 100% wave slots, doubling latency-hiding TLP.
//
// Datapath (verified; absmax pinned at the 2.441e-4 output-quantization floor):
//   layer 0: gates = x@W_ih0^T + (b_ih0+b_hh0)        (h=c=0, K padded 14->16)
//   layer l>=1: gates = h@(W_ih[l-1]+W_hh[l])^T + bc  (input==hidden quirk)
//   rows i,f,o scaled by -log2e (sigmoid=1/(1+exp2(y)));
//   rows g scaled by 2log2e (tanh=(exp2(y)-1)/(exp2(y)+1)).
//   W = fp16_hi + fp16_lo (22 bits), h = fp16; one v_mfma_f32_16x16x32_f16
//   with A=[Wh|Wl], B=[hf|hf] per gate-quadrant (K32 = two stacked K16 frags,
//   proven R7). Lane's D rows == its next-layer B k-slots (zero shuffles).

typedef _Float16 f16x8 __attribute__((ext_vector_type(8)));
typedef float f32x4 __attribute__((ext_vector_type(4)));
typedef float f32x2 __attribute__((ext_vector_type(2)));

#if __has_builtin(__builtin_amdgcn_mfma_f32_16x16x32_f16)
__device__ __forceinline__ f32x4 mfma32h(f16x8 a, f16x8 b, f32x4 c) {
    return __builtin_amdgcn_mfma_f32_16x16x32_f16(a, b, c, 0, 0, 0);
}
#else
__device__ __forceinline__ f32x4 mfma32h(f16x8 a, f16x8 b, f32x4 c) {
    asm volatile("v_mfma_f32_16x16x32_f16 %0, %1, %2, %0\n\ts_nop 7\n\ts_nop 7"
                 : "+v"(c) : "v"(a), "v"(b));
    return c;
}
#endif

#define NLOG2E  (-1.4426950408889634f)
#define G2LOG2E (2.8853900817779268f)
#define THREADS 1024
#define WAVES_PB (THREADS / 64)
#define NBLOCKS 512
#define NTILES 2

// LSTM nonlinearity on a pair of units (packed f32x2); rows pre-scaled.
__device__ __forceinline__ void act2(f32x2 yi, f32x2 yf, f32x2 yg, f32x2 yo,
                                     f32x2& c, f32x2& h) {
    f32x2 Ei, Ef, Eg, Eo;
    Ei[0] = __builtin_amdgcn_exp2f(yi[0]); Ei[1] = __builtin_amdgcn_exp2f(yi[1]);
    Ef[0] = __builtin_amdgcn_exp2f(yf[0]); Ef[1] = __builtin_amdgcn_exp2f(yf[1]);
    Eg[0] = __builtin_amdgcn_exp2f(yg[0]); Eg[1] = __builtin_amdgcn_exp2f(yg[1]);
    Eo[0] = __builtin_amdgcn_exp2f(yo[0]); Eo[1] = __builtin_amdgcn_exp2f(yo[1]);
    const f32x2 one = {1.f, 1.f};
    const f32x2 Di = Ei + one, Df = Ef + one, Do = Eo + one;
    const f32x2 P = __builtin_elementwise_fma(Di, Eg, Di);           // Di*(Eg+1)
    const f32x2 num = __builtin_elementwise_fma(
        Eg, Df, __builtin_elementwise_fma(c, P, -Df));               // (Eg-1)Df+cP
    const f32x2 DfP = Df * P;
    f32x2 R1;
    R1[0] = __builtin_amdgcn_rcpf(DfP[0]); R1[1] = __builtin_amdgcn_rcpf(DfP[1]);
    c = num * R1;
    const f32x2 cg = c * (f32x2){G2LOG2E, G2LOG2E};
    f32x2 Ec;
    Ec[0] = __builtin_amdgcn_exp2f(cg[0]); Ec[1] = __builtin_amdgcn_exp2f(cg[1]);
    const f32x2 Q = __builtin_elementwise_fma(Do, Ec, Do);           // Do*(Ec+1)
    f32x2 R2;
    R2[0] = __builtin_amdgcn_rcpf(Q[0]); R2[1] = __builtin_amdgcn_rcpf(Q[1]);
    h = __builtin_elementwise_fma(Ec, R2, -R2);                      // (Ec-1)/Q
}

#define LOP(v) __builtin_shufflevector(v, v, 0, 1)
#define HIP2(v) __builtin_shufflevector(v, v, 2, 3)

// duplicate-quad fp16 B fragment: [h0..h3 | h0..h3]
__device__ __forceinline__ f16x8 make_bfrag(f32x2 ha, f32x2 hb) {
    const _Float16 q0 = (_Float16)ha[0], q1 = (_Float16)ha[1];
    const _Float16 q2 = (_Float16)hb[0], q3 = (_Float16)hb[1];
    return (f16x8){q0, q1, q2, q3, q0, q1, q2, q3};
}

__global__ __launch_bounds__(THREADS, 2) void lstm_mfma_kernel(
    const float* __restrict__ x,      // [B][14]
    const float* __restrict__ W_ih0,  // [64][14]
    const float* __restrict__ W_ih,   // [7][64][16]
    const float* __restrict__ W_hh,   // [8][64][16]
    const float* __restrict__ b_ih,   // [8][64]
    const float* __restrict__ b_hh,   // [8][64]
    const float* __restrict__ fc_w,   // [16]
    const float* __restrict__ fc_b,   // [1]
    float* __restrict__ out,          // [B]
    int nB)
{
    // fragment-major: sWF[(l*4+t)*64 + lane] = 8 halfs [Wh0..3 | Wl0..3]
    __shared__ __align__(16) short sWF[8 * 4 * 64 * 8];  // 32 KB
    __shared__ __align__(16) float sB[8 * 64];
    __shared__ __align__(16) float sFC[20];

    const int tid = threadIdx.x;

    for (int slot = tid; slot < 2048; slot += THREADS) {
        const int l = slot >> 8;
        const int t = (slot >> 6) & 3;
        const int ln = slot & 63;
        const int row = t * 16 + (ln & 15);
        const int k0 = (ln >> 4) * 4;
        const float scale = (t == 2) ? G2LOG2E : NLOG2E;
        short frag[8];
        #pragma unroll
        for (int j = 0; j < 4; ++j) {
            const int k = k0 + j;
            float w;
            if (l == 0) w = (k < 14) ? W_ih0[row * 14 + k] : 0.0f;
            else        w = W_ih[(l - 1) * 1024 + row * 16 + k]
                          + W_hh[l * 1024 + row * 16 + k];
            w *= scale;
            const _Float16 wh = (_Float16)w;            // RNE fp16 hi
            const float wres = w - (float)wh;
            const _Float16 wl = (_Float16)wres;         // fp16 lo (22 bits total)
            frag[j]     = __builtin_bit_cast(short, wh);
            frag[4 + j] = __builtin_bit_cast(short, wl);
        }
        *(short4*)(sWF + slot * 8)     = make_short4(frag[0], frag[1], frag[2], frag[3]);
        *(short4*)(sWF + slot * 8 + 4) = make_short4(frag[4], frag[5], frag[6], frag[7]);
    }
    for (int idx = tid; idx < 512; idx += THREADS) {
        const int row = idx & 63;
        const float scale = ((row >> 4) == 2) ? G2LOG2E : NLOG2E;
        sB[idx] = (b_ih[idx] + b_hh[idx]) * scale;
    }
    if (tid < 16) sFC[tid] = fc_w[tid];
    if (tid == 16) sFC[16] = fc_b[0];
    __syncthreads();

    const int lane = tid & 63;
    const int wv = tid >> 6;
    const int bcol = lane & 15;   // batch within tile
    const int hi = lane >> 4;     // k-quad / D-row group

    const int n_grp = (nB + (16 * NTILES - 1)) / (16 * NTILES);
    const int waves_total = NBLOCKS * WAVES_PB;
    const int iters = (n_grp + waves_total - 1) / waves_total;
    const int gw = blockIdx.x * WAVES_PB + wv;

    const short* wbase = sWF + (lane << 3);
    const float* bbase = sB + hi * 4;

    const f32x4 fw4 = *(const f32x4*)(sFC + hi * 4);
    const f32x2 fwa = LOP(fw4), fwb = HIP2(fw4);
    const float fb = sFC[16];

    for (int it = 0; it < iters; ++it) {
        const int grp = gw * iters + it;
        if (grp >= n_grp) break;

        int bidx[NTILES];
        f32x2 ha[NTILES], hb[NTILES];
        f16x8 Bf[NTILES];
        f32x2 ca[NTILES], cb[NTILES];

        #pragma unroll
        for (int m = 0; m < NTILES; ++m) {
            const int b = grp * (16 * NTILES) + m * 16 + bcol;
            bidx[m] = b;
            const int bc = b < nB ? b : nB - 1;
            const float* xr = x + bc * 14 + hi * 4;
            const float2 p = *(const float2*)xr;
            ha[m][0] = p.x; ha[m][1] = p.y;
            if (hi < 3) {
                const float2 q = *(const float2*)(xr + 2);
                hb[m][0] = q.x; hb[m][1] = q.y;
            } else { hb[m] = (f32x2){0.f, 0.f}; }
            Bf[m] = make_bfrag(ha[m], hb[m]);
            ca[m] = (f32x2){0.f, 0.f};
            cb[m] = (f32x2){0.f, 0.f};
        }

        #pragma unroll
        for (int l = 0; l < 8; ++l) {
            // shared per-layer loads: 4 weight frags [Wh|Wl] + 4 bias quads
            f16x8 fr[4];
            f32x4 bias[4];
            #pragma unroll
            for (int t = 0; t < 4; ++t) {
                fr[t] = *(const f16x8*)(wbase + ((l * 4 + t) << 9));
                bias[t] = *(const f32x4*)(bbase + l * 64 + t * 16);
            }
            #pragma unroll
            for (int m = 0; m < NTILES; ++m) {
                f32x4 a[4];
                #pragma unroll
                for (int t = 0; t < 4; ++t) {
                    // (Wh+Wl)·hf in one K32 MFMA (two stacked K16 fragments)
                    a[t] = mfma32h(fr[t], Bf[m], bias[t]);
                }
                act2(LOP(a[0]), LOP(a[1]), LOP(a[2]), LOP(a[3]), ca[m], ha[m]);
                act2(HIP2(a[0]), HIP2(a[1]), HIP2(a[2]), HIP2(a[3]), cb[m], hb[m]);
                Bf[m] = make_bfrag(ha[m], hb[m]);
            }
        }

        // ---- FC head: dot(h, fc_w), reduce across 4 hi-lane groups ----
        #pragma unroll
        for (int m = 0; m < NTILES; ++m) {
            f32x2 s = ha[m] * fwa;
            s = __builtin_elementwise_fma(hb[m], fwb, s);
            float p = s[0] + s[1];
            p += __shfl_xor(p, 16, 64);
            p += __shfl_xor(p, 32, 64);
            if (hi == 0 && bidx[m] < nB) out[bidx[m]] = p + fb;
        }
    }
}

extern "C" void kernel_launch(void* const* d_in, const int* in_sizes, int n_in,
                              void* d_out, int out_size, void* d_ws, size_t ws_size,
                              hipStream_t stream) {
    const float* x     = (const float*)d_in[0];
    const float* W_ih0 = (const float*)d_in[1];
    const float* W_ih  = (const float*)d_in[2];
    const float* W_hh  = (const float*)d_in[3];
    const float* b_ih  = (const float*)d_in[4];
    const float* b_hh  = (const float*)d_in[5];
    const float* fc_w  = (const float*)d_in[6];
    const float* fc_b  = (const float*)d_in[7];
    float* out = (float*)d_out;

    const int B = in_sizes[0] / 14;
    lstm_mfma_kernel<<<NBLOCKS, THREADS, 0, stream>>>(
        x, W_ih0, W_ih, W_hh, b_ih, b_hh, fc_w, fc_b, out, B);
}